// Round 2
// baseline (1003.721 us; speedup 1.0000x reference)
//
#include <hip/hip_runtime.h>
#include <hip/hip_bf16.h>
#include <cstdint>
#include <cstddef>

// CoAttention on MI355X — round 4 (resubmit of R3; R3 bench died at the
// container level with no kernel-side evidence; schedule accounting
// re-verified, one hardening tweak added: sched_barrier(0) after each
// lgkmcnt(0) wait, per guide rule #18 / HK technique 4).
//
//   k=x@Wk^T; q_s=x@Wqs^T; q_o=queries@Wqo^T; v=values@Wv^T
//   S_s=q_s k^T/32+pen; S_o=q_o k^T/32+pen; p=softmax; out=(p_s+p_o)@v
// Outputs fp32 concat: out [8,2048,1024], p_self [8,2048,2048].
//
// gemm8: 256^2 8-phase template — T2 st-swizzle (XOR row&7 on 16B slots,
// applied via pre-swizzled GLOBAL source + linear global_load_lds dest +
// swizzled ds_read), T3/T4 8-phase counted vmcnt (2/4, never 0 in steady
// state), T5 setprio around MFMA clusters, T1 XCD-aware block swizzle.
// 8 waves (2Mx4N), per-wave 128x64 output, BK=64, 128 KiB LDS dbuf.
//
// Memory map (unchanged from R2):
//  ws [0,134MB):  phase1: xb(32M) qb(32M) vb(32M) W4(8M) bf16
//                 phase2: Ss bf16 [8,2048,2048] (67MB) | So bf16 (67MB);
//                         Psum bf16 written in-place over So
//  ws [134,166MB): Vt bf16 [8,1024,2048]
//  d_out ushort view: Qs@0, Qo@NE, Kb@2NE, Vtmp@3NE (all dead before the
//  final writes of out fp32 [0,64MB) and p_self fp32 [64,198MB)).

#define B_ 8
#define L_ 2048
#define D_ 1024

typedef __attribute__((ext_vector_type(8))) short short8;
typedef __attribute__((ext_vector_type(4))) float floatx4;

__device__ __forceinline__ ushort f2bf(float f) {
  union { float f; uint32_t u; } v; v.f = f;
  return (ushort)((v.u + 0x7FFFu + ((v.u >> 16) & 1u)) >> 16);
}
__device__ __forceinline__ float bf2f(ushort u) {
  union { uint32_t u; float f; } v; v.u = ((uint32_t)u) << 16;
  return v.f;
}

__device__ __forceinline__ void gload_lds16(const ushort* g, ushort* l) {
  __builtin_amdgcn_global_load_lds(
      (const __attribute__((address_space(1))) void*)g,
      (__attribute__((address_space(3))) void*)l, 16, 0, 0);
}

// Stage one half-tile (128 rows x 64 k-elems bf16 = 16KB) into LDS.
// LDS dest is LINEAR (required by global_load_lds: uniform base + lane*16B);
// the st-swizzle is applied by permuting the GLOBAL k-slot per (row&7), so
// LDS(row, slot) holds global k-slot (slot ^ (row&7)).  512 thr x 2 x 16B.
__device__ __forceinline__ void stage_half(
    const ushort* __restrict__ g, int stride, ushort* lds, int tid)
{
#pragma unroll
  for (int p = 0; p < 2; ++p) {
    const int grow  = p * 64 + (tid >> 3);
    const int gslot = (tid & 7) ^ (grow & 7);
    gload_lds16(g + grow * stride + gslot * 8, lds + p * 4096 + tid * 8);
  }
}

// Swizzled fragment read: 16B at (row, slot g) where LDS slot = g ^ (row&7).
// Consecutive 8 lanes (rows r..r+7) hit all 8 distinct 16B slots; bank =
// ((g^(row&7))*4 + w) % 32 covers all 32 banks per 8 rows -> 2-way max
// (free per m136), vs 8-16-way in the linear layout.
__device__ __forceinline__ short8 ldfrag(const ushort* L, int row, int g) {
  return *(const short8*)(L + row * 64 + ((g ^ (row & 7)) << 3));
}

#define MFMA_ __builtin_amdgcn_mfma_f32_16x16x32_bf16

// One phase: {ds_read subtile, stage half-tile, barrier, lgkmcnt(0),
// sched_barrier(0), setprio(1), 16 MFMA, setprio(0), [counted vmcnt],
// barrier}.  bufp/ks/nh/DOA are literals so all acc/af indices fold to
// constants.  asm("":::"memory") around barriers pins LDS ops to their
// phase (the raw s_barrier builtin is not a memory fence).
#define PHASE(bufp, ks, nh, DOA, STAGE_BLOCK, WAIT_BLOCK) do {               \
    if (DOA) {                                                               \
      const ushort* LA_ = lA[bufp];                                          \
      _Pragma("unroll")                                                      \
      for (int i_ = 0; i_ < 8; ++i_)                                         \
        af[i_] = ldfrag(LA_, wr * 128 + i_ * 16 + lan15, (ks) * 4 + lan4);   \
    }                                                                        \
    {                                                                        \
      const ushort* LB_ = lB[bufp];                                          \
      const int rb_ = wc * 64 + (nh) * 32 + lan15;                           \
      bf0 = ldfrag(LB_, rb_,      (ks) * 4 + lan4);                          \
      bf1 = ldfrag(LB_, rb_ + 16, (ks) * 4 + lan4);                          \
    }                                                                        \
    STAGE_BLOCK;                                                             \
    asm volatile("" ::: "memory");                                           \
    __builtin_amdgcn_s_barrier();                                            \
    asm volatile("s_waitcnt lgkmcnt(0)" ::: "memory");                       \
    __builtin_amdgcn_sched_barrier(0);                                       \
    __builtin_amdgcn_s_setprio(1);                                           \
    _Pragma("unroll")                                                        \
    for (int i_ = 0; i_ < 8; ++i_) {                                         \
      acc[i_][(nh) * 2]     = MFMA_(af[i_], bf0, acc[i_][(nh) * 2],     0, 0, 0); \
      acc[i_][(nh) * 2 + 1] = MFMA_(af[i_], bf1, acc[i_][(nh) * 2 + 1], 0, 0, 0); \
    }                                                                        \
    __builtin_amdgcn_s_setprio(0);                                           \
    WAIT_BLOCK;                                                              \
    asm volatile("" ::: "memory");                                           \
    __builtin_amdgcn_s_barrier();                                            \
    asm volatile("" ::: "memory");                                           \
  } while (0)

// C[M,N] = A[M,K] * B[N,K]^T, bf16 in, fp32 accum. 256x256 tile, BK=64,
// 8 waves (wr in {0,1} -> 128 rows, wc in {0..3} -> 64 cols).
// MODE 0 (proj):   asel={x,qry,x,val}, bsel=z (W order Wqs,Wqo,Wk,Wv), bf16 C
// MODE 1 (scores): bsel=msel=z&7, bf16 C = acc*scale + pen
// MODE 2 (out):    plain z, fp32 C
template<int MODE>
__global__ __launch_bounds__(512, 2) void gemm8(
    const ushort* __restrict__ A, long long aBatch, int aStride,
    const ushort* __restrict__ Bm, long long bBatch, int bStride,
    void* __restrict__ Cv, long long cBatch, int cStride,
    int K, const float* __restrict__ mask, float scale)
{
  __shared__ alignas(16) ushort lA[2][256 * 64];   // 32KB x2
  __shared__ alignas(16) ushort lB[2][256 * 64];   // 32KB x2  -> 128KB

  const int tid   = threadIdx.x;
  const int lane  = tid & 63;
  const int wave  = tid >> 6;
  const int wr    = wave >> 2;     // 0..1: row wave
  const int wc    = wave & 3;      // 0..3: col wave
  const int lan15 = lane & 15;
  const int lan4  = lane >> 4;

  // T1: XCD-aware swizzle of the flattened block index (all grids %8==0).
  const unsigned gx = gridDim.x, gy = gridDim.y;
  unsigned f = blockIdx.x + gx * (blockIdx.y + gy * blockIdx.z);
  const unsigned nwg = gx * gy * gridDim.z;
  f = (f & 7) * (nwg >> 3) + (f >> 3);
  const int bx = f % gx;
  const int by = (f / gx) % gy;
  const int bz = f / (gx * gy);

  int asel = bz, bsel = bz, msel = 0;
  if (MODE == 0) { asel = (bz & 1) + (bz == 3); }      // {0,1,0,2}: x,qry,x,val
  if (MODE == 1) { bsel = bz & 7; msel = bz & 7; }

  const ushort* Ab = A  + (long long)asel * aBatch + (long long)bx * 256 * aStride;
  const ushort* Bb = Bm + (long long)bsel * bBatch + (long long)by * 256 * bStride;

  const floatx4 zero = {0.f, 0.f, 0.f, 0.f};
  floatx4 acc[8][4];
#pragma unroll
  for (int i = 0; i < 8; i++)
#pragma unroll
    for (int j = 0; j < 4; j++) acc[i][j] = zero;

  const int NT  = K >> 6;       // BK=64 tiles (even for all our K)
  const int NIT = NT >> 1;      // iterations, 2 tiles each

  // Prologue: tile0 fully (buf0) + tile1 A-halves (buf1); leave tile1 A
  // in flight (vmcnt(4)) so the queue never drains.
  stage_half(Ab,                      aStride, &lA[0][0],    tid);
  stage_half(Ab + 128 * aStride,      aStride, &lA[0][8192], tid);
  stage_half(Bb,                      bStride, &lB[0][0],    tid);
  stage_half(Bb + 128 * bStride,      bStride, &lB[0][8192], tid);
  stage_half(Ab + 64,                 aStride, &lA[1][0],    tid);
  stage_half(Ab + 128 * aStride + 64, aStride, &lA[1][8192], tid);
  asm volatile("s_waitcnt vmcnt(4)" ::: "memory");
  __builtin_amdgcn_s_barrier();
  asm volatile("" ::: "memory");

  short8 af[8], bf0, bf1;

  for (int it = 0; it < NIT; ++it) {
    const int  t2   = it * 2;
    const bool full = (it < NIT - 1);
    const int  kB1  = (t2 + 1) << 6;   // tile t+1 k-offset (B halves)
    const int  kA2  = (t2 + 2) << 6;   // tile t+2
    const int  kA3  = (t2 + 3) << 6;   // tile t+3

    // Phases 1-4: tile t from buf0.  Stage slots chosen so each region's
    // last ds_read (+barrier) precedes its re-stage:
    //  buf1.B read last at prev ph5-8 -> stage B(t+1) at ph1/2
    //  buf0.A read at ph1(ks0)/ph3(ks1) -> stage A(t+2) at ph4/5
    //  buf0.B read ph1-4 -> stage B(t+2) at ph6/7
    //  buf1.A read ph5(ks0)/ph7(ks1) -> stage A(t+3) at ph8
    // vmcnt ledger (per wave, 2 loads per stage_half):
    //  enter iter: 4 in flight (A(t+1) from prev ph8/prologue)
    //  ph1 +2=6, ph2 +2=8, ph3 +0, ph4 +2=10 -> vmcnt(2) retires
    //  A(t+1)+B(t+1)=8, leaves ph4's 2.
    PHASE(0, 0, 0, true,
          { stage_half(Bb + kB1, bStride, &lB[1][0], tid); }, {});
    PHASE(0, 0, 1, false,
          { stage_half(Bb + 128 * bStride + kB1, bStride, &lB[1][8192], tid); }, {});
    PHASE(0, 1, 0, true, {}, {});
    PHASE(0, 1, 1, false,
          { if (full) stage_half(Ab + kA2, aStride, &lA[0][0], tid); },
          { if (full) { asm volatile("s_waitcnt vmcnt(2)" ::: "memory"); }
            else      { asm volatile("s_waitcnt vmcnt(0)" ::: "memory"); } });

    // Phases 5-8: tile t+1 from buf1.
    //  ph5 +2=4, ph6 +2=6, ph7 +2=8, ph8 +4=12 -> vmcnt(4) retires
    //  A(t+2)+B(t+2)=8, leaves A(t+3)'s 4 in flight across the back-edge.
    PHASE(1, 0, 0, true,
          { if (full) stage_half(Ab + 128 * aStride + kA2, aStride, &lA[0][8192], tid); }, {});
    PHASE(1, 0, 1, false,
          { if (full) stage_half(Bb + kA2, bStride, &lB[0][0], tid); }, {});
    PHASE(1, 1, 0, true,
          { if (full) stage_half(Bb + 128 * bStride + kA2, bStride, &lB[0][8192], tid); }, {});
    PHASE(1, 1, 1, false,
          { if (full) { stage_half(Ab + kA3, aStride, &lA[1][0], tid);
                        stage_half(Ab + 128 * aStride + kA3, aStride, &lA[1][8192], tid); } },
          { if (full) { asm volatile("s_waitcnt vmcnt(4)" ::: "memory"); } });
  }

  // C/D layout (m89): col = lane&15, row = (lane>>4)*4 + r
  const int m0 = bx * 256 + wr * 128 + (lane >> 4) * 4;
  const int n0 = by * 256 + wc * 64 + (lane & 15);

  if (MODE == 2) {
    float* C = (float*)Cv + (long long)bz * cBatch;
#pragma unroll
    for (int i = 0; i < 8; i++)
#pragma unroll
      for (int n = 0; n < 4; n++)
#pragma unroll
        for (int r = 0; r < 4; r++)
          C[(long long)(m0 + i * 16 + r) * cStride + (n0 + n * 16)] = acc[i][n][r];
  } else {
    ushort* C = (ushort*)Cv + (long long)bz * cBatch;
#pragma unroll
    for (int n = 0; n < 4; n++) {
      const int gc = n0 + n * 16;
      float pen = 0.f;
      if (MODE == 1) pen = (1.0f - mask[(long long)msel * L_ + gc]) * -100000.0f;
#pragma unroll
      for (int i = 0; i < 8; i++)
#pragma unroll
        for (int r = 0; r < 4; r++) {
          float v = acc[i][n][r];
          if (MODE == 1) v = v * scale + pen;
          C[(long long)(m0 + i * 16 + r) * cStride + gc] = f2bf(v);
        }
    }
  }
}

// Vt[b][a][k] = V[b][k][a]  (bf16), 64x64 LDS tiles
__global__ __launch_bounds__(256) void transpose_bf16(
    const ushort* __restrict__ V, ushort* __restrict__ Vt)
{
  __shared__ ushort t[64][66];
  const int b = blockIdx.z;
  const int k0 = blockIdx.x * 64;
  const int a0 = blockIdx.y * 64;
  const ushort* Vb = V + (size_t)b * (L_ * D_);
  ushort* Vtb = Vt + (size_t)b * (D_ * L_);
  const int tx = threadIdx.x & 63;
  const int ty = threadIdx.x >> 6;
#pragma unroll
  for (int r = 0; r < 16; ++r) {
    int row = r * 4 + ty;
    t[row][tx] = Vb[(size_t)(k0 + row) * D_ + (a0 + tx)];
  }
  __syncthreads();
#pragma unroll
  for (int r = 0; r < 16; ++r) {
    int row = r * 4 + ty;
    Vtb[(size_t)(a0 + row) * L_ + (k0 + tx)] = t[tx][row];
  }
}

__device__ __forceinline__ float block_red(float v, bool domax, float* red)
{
#pragma unroll
  for (int off = 32; off > 0; off >>= 1) {
    float o = __shfl_xor(v, off, 64);
    v = domax ? fmaxf(v, o) : (v + o);
  }
  __syncthreads();
  if ((threadIdx.x & 63) == 0) red[threadIdx.x >> 6] = v;
  __syncthreads();
  return domax ? fmaxf(fmaxf(red[0], red[1]), fmaxf(red[2], red[3]))
               : (red[0] + red[1] + red[2] + red[3]);
}

// One workgroup per row. Reads Ss,So (bf16, 8 elems/thread via uint4).
// Writes p_self fp32 and Psum bf16 (in-place over So).
__global__ __launch_bounds__(256) void softmax2(
    const ushort* __restrict__ S, float* __restrict__ pself)
{
  __shared__ float red[4];
  const size_t row = blockIdx.x;
  const int tid = threadIdx.x;
  const size_t half = (size_t)B_ * L_ * L_;

  const uint4* rs = (const uint4*)(S + row * L_);
  const uint4* ro = (const uint4*)(S + half + row * L_);
  uint4 us = rs[tid];
  uint4 uo = ro[tid];

  float vs[8], vo[8];
  const ushort* ps = (const ushort*)&us;
  const ushort* po = (const ushort*)&uo;
#pragma unroll
  for (int j = 0; j < 8; j++) { vs[j] = bf2f(ps[j]); vo[j] = bf2f(po[j]); }

  float ms = -3.0e38f, mo = -3.0e38f;
#pragma unroll
  for (int j = 0; j < 8; j++) { ms = fmaxf(ms, vs[j]); mo = fmaxf(mo, vo[j]); }
  ms = block_red(ms, true, red);
  mo = block_red(mo, true, red);

  float ss = 0.f, so = 0.f;
#pragma unroll
  for (int j = 0; j < 8; j++) {
    vs[j] = __expf(vs[j] - ms); ss += vs[j];
    vo[j] = __expf(vo[j] - mo); so += vo[j];
  }
  ss = block_red(ss, false, red);
  so = block_red(so, false, red);
  const float is = 1.f / ss, io = 1.f / so;

  float* pr = pself + row * (size_t)L_ + (size_t)tid * 8;
  float4 o0, o1;
  o0.x = vs[0] * is; o0.y = vs[1] * is; o0.z = vs[2] * is; o0.w = vs[3] * is;
  o1.x = vs[4] * is; o1.y = vs[5] * is; o1.z = vs[6] * is; o1.w = vs[7] * is;
  ((float4*)pr)[0] = o0;
  ((float4*)pr)[1] = o1;

  uint4 up;
  ushort* pp = (ushort*)&up;
#pragma unroll
  for (int j = 0; j < 8; j++) pp[j] = f2bf(vs[j] * is + vo[j] * io);
  ((uint4*)(S + half + row * L_))[tid] = up;   // in-place over So (all reads done)
}

// fp32 -> bf16, blockIdx.z selects source; dst slabs contiguous (n4*4 each)
__global__ __launch_bounds__(256) void cvt4(
    const float* __restrict__ s0, const float* __restrict__ s1,
    const float* __restrict__ s2, const float* __restrict__ s3,
    ushort* __restrict__ dst, int n4)
{
  const float* s = (blockIdx.z == 0) ? s0 : (blockIdx.z == 1) ? s1
                   : (blockIdx.z == 2) ? s2 : s3;
  ushort* d = dst + (size_t)blockIdx.z * (size_t)n4 * 4;
  const float4* sv = (const float4*)s;
  ushort4* dv = (ushort4*)d;
  for (int i = blockIdx.x * 256 + threadIdx.x; i < n4; i += gridDim.x * 256) {
    float4 f = sv[i];
    ushort4 o; o.x = f2bf(f.x); o.y = f2bf(f.y); o.z = f2bf(f.z); o.w = f2bf(f.w);
    dv[i] = o;
  }
}

extern "C" void kernel_launch(void* const* d_in, const int* in_sizes, int n_in,
                              void* d_out, int out_size, void* d_ws, size_t ws_size,
                              hipStream_t stream)
{
  const float* x    = (const float*)d_in[0];
  const float* qry  = (const float*)d_in[1];
  const float* val  = (const float*)d_in[2];
  const float* mask = (const float*)d_in[3];
  const float* Wk   = (const float*)d_in[4];
  const float* Wqs  = (const float*)d_in[5];
  const float* Wqo  = (const float*)d_in[6];
  const float* Wv   = (const float*)d_in[7];

  const size_t NE = (size_t)B_ * L_ * D_;    // 16,777,216
  const size_t NW = (size_t)D_ * D_;         // 1,048,576
  const size_t NS = (size_t)B_ * L_ * L_;    // 33,554,432 (one score set)

  float*  out   = (float*)d_out;
  float*  pself = out + NE;                  // [8,2048,2048] fp32

  ushort* ob = (ushort*)d_out;               // ushort view of d_out
  ushort* Qs   = ob;                         // [0, NE)
  ushort* Qo   = ob + NE;                    // [NE, 2NE)
  ushort* Kb   = ob + 2 * NE;                // [2NE, 3NE)  (in p_self region)
  ushort* Vtmp = ob + 3 * NE;                // [3NE, 4NE)

  char* ws = (char*)d_ws;
  ushort* xb = (ushort*)ws;                  // phase-1: xb qb vb W4
  ushort* W4 = xb + 3 * NE;
  ushort* Sc = (ushort*)ws;                  // phase-2: Ss | So (then Psum)
  ushort* Psum = Sc + NS;                    // = So, bf16 in place
  ushort* Vt = (ushort*)(ws + (size_t)134217728);

  const float scale = 0.03125f;              // 1/sqrt(1024)

  // 1) fp32 -> bf16 (weights in proj order: Wqs, Wqo, Wk, Wv)
  cvt4<<<dim3(4096, 1, 3), 256, 0, stream>>>(x, qry, val, nullptr, xb, (int)(NE / 4));
  cvt4<<<dim3(1024, 1, 4), 256, 0, stream>>>(Wqs, Wqo, Wk, Wv, W4, (int)(NW / 4));

  // 2) projections, merged: z=0..3 -> Qs, Qo, Kb, Vtmp; M=16384,N=1024,K=1024
  gemm8<0><<<dim3(64, 4, 4), 512, 0, stream>>>(
      xb, (long long)NE, D_, W4, (long long)NW, D_,
      ob, (long long)NE, D_, D_, nullptr, 1.f);

  // 3) V -> V^T
  transpose_bf16<<<dim3(L_ / 64, D_ / 64, B_), 256, 0, stream>>>(Vtmp, Vt);

  // 4) scores, merged: z=0..15 (z<8: Qs->Ss, z>=8: Qo->So); M=N=2048,K=1024
  gemm8<1><<<dim3(8, 8, 16), 512, 0, stream>>>(
      Qs, (long long)L_ * D_, D_, Kb, (long long)L_ * D_, D_,
      Sc, (long long)L_ * L_, L_, D_, mask, scale);

  // 5) softmax both sets; p_self fp32; Psum bf16 in place over So
  softmax2<<<dim3(B_ * L_, 1, 1), 256, 0, stream>>>(Sc, pself);

  // 6) out = Psum @ Vt^T: M=2048, N=1024, K=2048, z=0..7
  gemm8<2><<<dim3(8, 4, 8), 512, 0, stream>>>(
      Psum, (long long)L_ * L_, L_, Vt, (long long)D_ * L_, L_,
      out, (long long)L_ * D_, D_, L_, nullptr, 1.f);
}